// Round 1
// baseline (449.811 us; speedup 1.0000x reference)
//
#include <hip/hip_runtime.h>
#include <hip/hip_bf16.h>
#include <math.h>

#define KEY_DIM   512
#define VALUE_DIM 128
#define CAPACITY  500000
#define NRET      32
#define LN_EPS    1e-5f
#define NORM_EPS  1e-12f
#define NEG_INF   (-3.402823466e38f)

#define SCAN_BLOCKS 1024
#define CHUNK       489   // ceil(500000 / 1024); 1024*489 = 500736 >= 500000

// ---------------- helpers ----------------

__device__ inline float blockSum512(float v, float* red) {
  #pragma unroll
  for (int off = 32; off; off >>= 1) v += __shfl_xor(v, off);
  int wid = threadIdx.x >> 6, lane = threadIdx.x & 63;
  if (lane == 0) red[wid] = v;
  __syncthreads();
  float s = red[0] + red[1] + red[2] + red[3] + red[4] + red[5] + red[6] + red[7];
  __syncthreads();   // red may be reused by caller
  return s;
}

// argmax over the 64 lanes of a wave; (v, p): prefer larger v, then smaller p
__device__ inline void waveArgMaxPair(float& v, int& p) {
  #pragma unroll
  for (int off = 32; off; off >>= 1) {
    float ov = __shfl_xor(v, off);
    int   op = __shfl_xor(p, off);
    if (ov > v || (ov == v && op < p)) { v = ov; p = op; }
  }
}

// argmax with carried global index gi and local pos p; compare by (v, gi)
__device__ inline void waveArgMaxTriple(float& v, int& gi, int& p) {
  #pragma unroll
  for (int off = 32; off; off >>= 1) {
    float ov  = __shfl_xor(v, off);
    int   ogi = __shfl_xor(gi, off);
    int   op  = __shfl_xor(p, off);
    if (ov > v || (ov == v && ogi < gi)) { v = ov; gi = ogi; p = op; }
  }
}

// ---------------- kernel 1: MLP + LN + L2-normalize ----------------
// one block, 512 threads (8 waves); wave w computes rows [w*64, w*64+64)

__global__ __launch_bounds__(512) void mlp_kernel(
    const float* __restrict__ query, const float* __restrict__ W1, const float* __restrict__ b1,
    const float* __restrict__ W2, const float* __restrict__ b2,
    const float* __restrict__ ln_g, const float* __restrict__ ln_b,
    float* __restrict__ qn)
{
  __shared__ float qs[512];
  __shared__ float hs[512];
  __shared__ float red[8];
  int tid = threadIdx.x;
  int wid = tid >> 6, lane = tid & 63;

  qs[tid] = query[tid];
  __syncthreads();

  // matvec1: h = silu(q @ W1^T + b1)
  {
    const float4* qs4 = reinterpret_cast<const float4*>(qs);
    for (int r = 0; r < 64; ++r) {
      int row = (wid << 6) + r;
      const float4* wrow = reinterpret_cast<const float4*>(W1 + (size_t)row * 512);
      float acc = 0.f;
      #pragma unroll
      for (int k = 0; k < 2; ++k) {
        float4 a = wrow[lane + 64 * k];
        float4 q = qs4[lane + 64 * k];
        acc += a.x * q.x + a.y * q.y + a.z * q.z + a.w * q.w;
      }
      #pragma unroll
      for (int off = 32; off; off >>= 1) acc += __shfl_xor(acc, off);
      if (lane == 0) {
        float x = acc + b1[row];
        hs[row] = x / (1.f + expf(-x));   // silu
      }
    }
  }
  __syncthreads();

  // matvec2: g = h @ W2^T + b2  -> stored back into qs (query no longer needed)
  {
    const float4* hs4 = reinterpret_cast<const float4*>(hs);
    for (int r = 0; r < 64; ++r) {
      int row = (wid << 6) + r;
      const float4* wrow = reinterpret_cast<const float4*>(W2 + (size_t)row * 512);
      float acc = 0.f;
      #pragma unroll
      for (int k = 0; k < 2; ++k) {
        float4 a = wrow[lane + 64 * k];
        float4 h = hs4[lane + 64 * k];
        acc += a.x * h.x + a.y * h.y + a.z * h.z + a.w * h.w;
      }
      #pragma unroll
      for (int off = 32; off; off >>= 1) acc += __shfl_xor(acc, off);
      if (lane == 0) qs[row] = acc + b2[row];
    }
  }
  __syncthreads();

  // LayerNorm + L2 normalize
  float x  = qs[tid];
  float mu = blockSum512(x, red) * (1.f / 512.f);
  float d  = x - mu;
  float var = blockSum512(d * d, red) * (1.f / 512.f);
  float y  = d * (1.f / sqrtf(var + LN_EPS)) * ln_g[tid] + ln_b[tid];
  float nsq = blockSum512(y * y, red);
  float n  = fmaxf(sqrtf(nsq), NORM_EPS);
  qn[tid] = y / n;
}

// ---------------- kernel 2: cosine-sim scan + per-block top-32 ----------------
// grid SCAN_BLOCKS x 256; one wave per key row (2 x float4 per lane)

__global__ __launch_bounds__(256) void scan_topk(
    const float* __restrict__ keys, const float* __restrict__ qn,
    float* __restrict__ cand_val, int* __restrict__ cand_idx, int C)
{
  __shared__ float ssim[CHUNK];
  __shared__ float redv[4];
  __shared__ int   redp[4];
  int tid = threadIdx.x;
  int wid = tid >> 6, lane = tid & 63;
  int s0  = blockIdx.x * CHUNK;
  int cnt = min(CHUNK, C - s0);       // may be <= 0 for the last block

  float4 q0 = ((const float4*)qn)[lane];
  float4 q1 = ((const float4*)qn)[lane + 64];
  const float4* keys4 = (const float4*)keys;

  for (int lr = wid; lr < cnt; lr += 4) {
    size_t rb = (size_t)(s0 + lr) * 128;
    float4 a = keys4[rb + lane];
    float4 c = keys4[rb + 64 + lane];
    float dot = a.x * q0.x + a.y * q0.y + a.z * q0.z + a.w * q0.w
              + c.x * q1.x + c.y * q1.y + c.z * q1.z + c.w * q1.w;
    float ss  = a.x * a.x + a.y * a.y + a.z * a.z + a.w * a.w
              + c.x * c.x + c.y * c.y + c.z * c.z + c.w * c.w;
    #pragma unroll
    for (int off = 32; off; off >>= 1) {
      dot += __shfl_xor(dot, off);
      ss  += __shfl_xor(ss, off);
    }
    if (lane == 0) ssim[lr] = dot / fmaxf(sqrtf(ss), NORM_EPS);
  }
  __syncthreads();

  for (int it = 0; it < NRET; ++it) {
    float bv = NEG_INF; int bp = 0x7fffffff;
    for (int p = tid; p < cnt; p += 256) {
      float vv = ssim[p];
      if (vv > bv || (vv == bv && p < bp)) { bv = vv; bp = p; }
    }
    waveArgMaxPair(bv, bp);
    if (lane == 0) { redv[wid] = bv; redp[wid] = bp; }
    __syncthreads();
    if (tid == 0) {
      float v = redv[0]; int p = redp[0];
      #pragma unroll
      for (int i = 1; i < 4; ++i)
        if (redv[i] > v || (redv[i] == v && redp[i] < p)) { v = redv[i]; p = redp[i]; }
      int ok = (p < cnt);
      cand_val[blockIdx.x * NRET + it] = ok ? v : NEG_INF;
      cand_idx[blockIdx.x * NRET + it] = ok ? (s0 + p) : 0;
      if (ok) ssim[p] = NEG_INF;
    }
    __syncthreads();
  }
}

// ---------------- kernel 3: merge 32768 candidates -> 1024 ----------------
// 32 blocks x 256; block m reduces candidates [m*1024, (m+1)*1024) to its top-32

__global__ __launch_bounds__(256) void merge_topk(
    const float* __restrict__ cand_val, const int* __restrict__ cand_idx,
    float* __restrict__ c2v, int* __restrict__ c2i)
{
  __shared__ float cv[1024];
  __shared__ int   ci[1024];
  __shared__ float redv[4];
  __shared__ int   redg[4];
  __shared__ int   redp[4];
  int tid = threadIdx.x;
  int wid = tid >> 6, lane = tid & 63;
  int base = blockIdx.x * 1024;
  for (int t = tid; t < 1024; t += 256) { cv[t] = cand_val[base + t]; ci[t] = cand_idx[base + t]; }
  __syncthreads();

  for (int it = 0; it < NRET; ++it) {
    float bv = NEG_INF; int bg = 0x7fffffff; int bp = -1;
    for (int p = tid; p < 1024; p += 256) {
      float vv = cv[p]; int gg = ci[p];
      if (vv > bv || (vv == bv && gg < bg)) { bv = vv; bg = gg; bp = p; }
    }
    waveArgMaxTriple(bv, bg, bp);
    if (lane == 0) { redv[wid] = bv; redg[wid] = bg; redp[wid] = bp; }
    __syncthreads();
    if (tid == 0) {
      float v = redv[0]; int g = redg[0]; int p = redp[0];
      #pragma unroll
      for (int i = 1; i < 4; ++i)
        if (redv[i] > v || (redv[i] == v && redg[i] < g)) { v = redv[i]; g = redg[i]; p = redp[i]; }
      c2v[blockIdx.x * NRET + it] = v;
      c2i[blockIdx.x * NRET + it] = g;
      if (p >= 0) cv[p] = NEG_INF;
    }
    __syncthreads();
  }
}

// ---------------- kernel 4: final top-32 + softmax + weighted gather ----------------

__global__ __launch_bounds__(256) void final_kernel(
    const float* __restrict__ c2v, const int* __restrict__ c2i,
    const float* __restrict__ values, float* __restrict__ out)
{
  __shared__ float cv[1024];
  __shared__ int   ci[1024];
  __shared__ float redv[4];
  __shared__ int   redg[4];
  __shared__ int   redp[4];
  __shared__ float selv[NRET];
  __shared__ int   seli[NRET];
  __shared__ float attn[NRET];
  int tid = threadIdx.x;
  int wid = tid >> 6, lane = tid & 63;
  for (int t = tid; t < 1024; t += 256) { cv[t] = c2v[t]; ci[t] = c2i[t]; }
  __syncthreads();

  for (int it = 0; it < NRET; ++it) {
    float bv = NEG_INF; int bg = 0x7fffffff; int bp = -1;
    for (int p = tid; p < 1024; p += 256) {
      float vv = cv[p]; int gg = ci[p];
      if (vv > bv || (vv == bv && gg < bg)) { bv = vv; bg = bg > gg ? bg : bg, bp = bp; } // never taken path guard
      if (vv > bv || (vv == bv && gg < bg)) { bv = vv; bg = gg; bp = p; }
    }
    // NOTE: the first if above is defensive dead code; redo the scan cleanly:
    bv = NEG_INF; bg = 0x7fffffff; bp = -1;
    for (int p = tid; p < 1024; p += 256) {
      float vv = cv[p]; int gg = ci[p];
      if (vv > bv || (vv == bv && gg < bg)) { bv = vv; bg = gg; bp = p; }
    }
    waveArgMaxTriple(bv, bg, bp);
    if (lane == 0) { redv[wid] = bv; redg[wid] = bg; redp[wid] = bp; }
    __syncthreads();
    if (tid == 0) {
      float v = redv[0]; int g = redg[0]; int p = redp[0];
      #pragma unroll
      for (int i = 1; i < 4; ++i)
        if (redv[i] > v || (redv[i] == v && redg[i] < g)) { v = redv[i]; g = redg[i]; p = redp[i]; }
      selv[it] = v; seli[it] = g;
      if (p >= 0) cv[p] = NEG_INF;
    }
    __syncthreads();
  }

  // softmax over the 32 selected sims (selv[0] is the global max)
  if (tid < NRET) {
    float e = expf(selv[tid] - selv[0]);
    float s = e;
    #pragma unroll
    for (int off = 16; off; off >>= 1) s += __shfl_xor(s, off);
    attn[tid] = e / s;
  }
  __syncthreads();

  // weighted sum of gathered value rows
  if (tid < VALUE_DIM) {
    float acc = 0.f;
    #pragma unroll
    for (int k = 0; k < NRET; ++k)
      acc += attn[k] * values[(size_t)seli[k] * VALUE_DIM + tid];
    out[tid] = acc;
  }
}

// ---------------- launch ----------------

extern "C" void kernel_launch(void* const* d_in, const int* in_sizes, int n_in,
                              void* d_out, int out_size, void* d_ws, size_t ws_size,
                              hipStream_t stream) {
  const float* query  = (const float*)d_in[0];
  const float* W1     = (const float*)d_in[1];
  const float* b1     = (const float*)d_in[2];
  const float* W2     = (const float*)d_in[3];
  const float* b2     = (const float*)d_in[4];
  const float* ln_g   = (const float*)d_in[5];
  const float* ln_b   = (const float*)d_in[6];
  const float* keys   = (const float*)d_in[7];
  const float* values = (const float*)d_in[8];
  float* out = (float*)d_out;

  float* wsf      = (float*)d_ws;
  float* qn       = wsf;                         // 512
  float* cand_val = wsf + 512;                   // 32768
  int*   cand_idx = (int*)(wsf + 512 + 32768);   // 32768
  float* c2v      = wsf + 512 + 65536;           // 1024
  int*   c2i      = (int*)(wsf + 512 + 65536 + 1024); // 1024

  hipLaunchKernelGGL(mlp_kernel, dim3(1), dim3(512), 0, stream,
                     query, W1, b1, W2, b2, ln_g, ln_b, qn);
  hipLaunchKernelGGL(scan_topk, dim3(SCAN_BLOCKS), dim3(256), 0, stream,
                     keys, qn, cand_val, cand_idx, CAPACITY);
  hipLaunchKernelGGL(merge_topk, dim3(32), dim3(256), 0, stream,
                     cand_val, cand_idx, c2v, c2i);
  hipLaunchKernelGGL(final_kernel, dim3(1), dim3(256), 0, stream,
                     c2v, c2i, values, out);
}

// Round 2
// 309.013 us; speedup vs baseline: 1.4556x; 1.4556x over previous
//
#include <hip/hip_runtime.h>
#include <hip/hip_bf16.h>
#include <math.h>

#define KEY_DIM   512
#define VALUE_DIM 128
#define CAPACITY  500000
#define NRET      32
#define LN_EPS    1e-5f
#define NORM_EPS  1e-12f
#define NEG_INF   (-3.402823466e38f)

#define SCAN_BLOCKS 1024
#define CHUNK       489   // ceil(500000 / 1024); per-wave rows <= 123 (fits 2 regs/lane)

// ---------------- helpers ----------------

__device__ inline float blockSum512(float v, float* red) {
  #pragma unroll
  for (int off = 32; off; off >>= 1) v += __shfl_xor(v, off);
  int wid = threadIdx.x >> 6, lane = threadIdx.x & 63;
  if (lane == 0) red[wid] = v;
  __syncthreads();
  float s = red[0] + red[1] + red[2] + red[3] + red[4] + red[5] + red[6] + red[7];
  __syncthreads();
  return s;
}

// butterfly argmax over 64 lanes by (v desc, gi asc); carries a payload code
__device__ inline void waveArgMax3(float& v, int& gi, int& code) {
  #pragma unroll
  for (int off = 32; off; off >>= 1) {
    float ov = __shfl_xor(v, off);
    int   og = __shfl_xor(gi, off);
    int   oc = __shfl_xor(code, off);
    if (ov > v || (ov == v && og < gi)) { v = ov; gi = og; code = oc; }
  }
}

// ---------------- MLP kernels (parallel matvecs) ----------------
// grid 128 x 256: wave w computes out[row], row = blockIdx*4 + wid

__global__ __launch_bounds__(256) void matvec1_kernel(
    const float* __restrict__ query, const float* __restrict__ W1,
    const float* __restrict__ b1, float* __restrict__ h)
{
  int tid = threadIdx.x, wid = tid >> 6, lane = tid & 63;
  int row = (blockIdx.x << 2) + wid;
  const float4* q4 = (const float4*)query;
  const float4* wrow = (const float4*)(W1 + (size_t)row * KEY_DIM);
  float4 a0 = wrow[lane],      q0 = q4[lane];
  float4 a1 = wrow[lane + 64], q1 = q4[lane + 64];
  float acc = a0.x*q0.x + a0.y*q0.y + a0.z*q0.z + a0.w*q0.w
            + a1.x*q1.x + a1.y*q1.y + a1.z*q1.z + a1.w*q1.w;
  #pragma unroll
  for (int off = 32; off; off >>= 1) acc += __shfl_xor(acc, off);
  if (lane == 0) {
    float x = acc + b1[row];
    h[row] = x / (1.f + expf(-x));   // silu
  }
}

__global__ __launch_bounds__(256) void matvec2_kernel(
    const float* __restrict__ h, const float* __restrict__ W2,
    const float* __restrict__ b2, float* __restrict__ g)
{
  int tid = threadIdx.x, wid = tid >> 6, lane = tid & 63;
  int row = (blockIdx.x << 2) + wid;
  const float4* h4 = (const float4*)h;
  const float4* wrow = (const float4*)(W2 + (size_t)row * KEY_DIM);
  float4 a0 = wrow[lane],      q0 = h4[lane];
  float4 a1 = wrow[lane + 64], q1 = h4[lane + 64];
  float acc = a0.x*q0.x + a0.y*q0.y + a0.z*q0.z + a0.w*q0.w
            + a1.x*q1.x + a1.y*q1.y + a1.z*q1.z + a1.w*q1.w;
  #pragma unroll
  for (int off = 32; off; off >>= 1) acc += __shfl_xor(acc, off);
  if (lane == 0) g[row] = acc + b2[row];
}

// 1 block x 512: LayerNorm + L2 normalize
__global__ __launch_bounds__(512) void norm_kernel(
    const float* __restrict__ g, const float* __restrict__ ln_g,
    const float* __restrict__ ln_b, float* __restrict__ qn)
{
  __shared__ float red[8];
  int tid = threadIdx.x;
  float x  = g[tid];
  float mu = blockSum512(x, red) * (1.f / 512.f);
  float d  = x - mu;
  float var = blockSum512(d * d, red) * (1.f / 512.f);
  float y  = d * (1.f / sqrtf(var + LN_EPS)) * ln_g[tid] + ln_b[tid];
  float nsq = blockSum512(y * y, red);
  float n  = fmaxf(sqrtf(nsq), NORM_EPS);
  qn[tid] = y / n;
}

// ---------------- kernel: cosine-sim scan + per-WAVE top-32 (no LDS, no barriers) ----------------
// grid SCAN_BLOCKS x 256; wave wid handles rows s0 + wid + 4*j, j = 0..nrow-1 (nrow <= 123)
// sims kept in 2 registers/lane: slot0 lane l <- j=l, slot1 lane l <- j=64+l

__global__ __launch_bounds__(256) void scan_topk(
    const float* __restrict__ keys, const float* __restrict__ qn,
    float* __restrict__ cand_val, int* __restrict__ cand_idx, int C)
{
  int tid = threadIdx.x, wid = tid >> 6, lane = tid & 63;
  int s0  = blockIdx.x * CHUNK;
  int cnt = min(CHUNK, C - s0);                       // may be <= 0 for tail blocks
  int nrow = (cnt > wid) ? ((cnt - wid + 3) >> 2) : 0;

  const float4* q4 = (const float4*)qn;
  float4 q0 = q4[lane];
  float4 q1 = q4[lane + 64];
  const float4* keys4 = (const float4*)keys;

  float v0 = NEG_INF, v1 = NEG_INF;

  #pragma unroll 2
  for (int j = 0; j < nrow; ++j) {
    size_t rb = (size_t)(s0 + wid + (j << 2)) * 128;  // float4 units: 512 floats/row
    float4 a = keys4[rb + lane];
    float4 c = keys4[rb + 64 + lane];
    float dot = a.x*q0.x + a.y*q0.y + a.z*q0.z + a.w*q0.w
              + c.x*q1.x + c.y*q1.y + c.z*q1.z + c.w*q1.w;
    float ss  = a.x*a.x + a.y*a.y + a.z*a.z + a.w*a.w
              + c.x*c.x + c.y*c.y + c.z*c.z + c.w*c.w;
    #pragma unroll
    for (int off = 32; off; off >>= 1) {
      dot += __shfl_xor(dot, off);
      ss  += __shfl_xor(ss, off);
    }
    float sim = dot / fmaxf(sqrtf(ss), NORM_EPS);     // broadcast to all 64 lanes
    bool mine = (lane == (j & 63));
    if (j < 64) { if (mine) v0 = sim; }
    else        { if (mine) v1 = sim; }
  }

  // per-wave top-32 register tournament
  int gbase = s0 + wid;
  int out0 = ((blockIdx.x << 2) + wid) * NRET;
  for (int it = 0; it < NRET; ++it) {
    bool pick1 = (v1 > v0);                            // tie -> slot0 (smaller gi)
    float v = pick1 ? v1 : v0;
    int slot = pick1 ? 1 : 0;
    int gi = gbase + ((lane + (slot << 6)) << 2);
    int code = (lane << 1) | slot;
    waveArgMax3(v, gi, code);
    if (lane == (code >> 1)) {
      if (code & 1) v1 = NEG_INF; else v0 = NEG_INF;
    }
    if (lane == 0) {
      cand_val[out0 + it] = v;
      cand_idx[out0 + it] = v > NEG_INF ? gi : 0x7ffffff0;
    }
  }
}

// ---------------- merge: per block, 1024 candidates -> top-32 ----------------

__global__ __launch_bounds__(256) void merge_topk(
    const float* __restrict__ in_val, const int* __restrict__ in_idx,
    float* __restrict__ out_val, int* __restrict__ out_idx)
{
  __shared__ float cv[1024];
  __shared__ int   ci[1024];
  __shared__ float redv[4];
  __shared__ int   redg[4];
  __shared__ int   redp[4];
  int tid = threadIdx.x, wid = tid >> 6, lane = tid & 63;
  int base = blockIdx.x << 10;
  for (int t = tid; t < 1024; t += 256) { cv[t] = in_val[base + t]; ci[t] = in_idx[base + t]; }
  __syncthreads();

  for (int it = 0; it < NRET; ++it) {
    float bv = NEG_INF; int bg = 0x7fffffff; int bp = -1;
    #pragma unroll
    for (int k = 0; k < 4; ++k) {
      int p = tid + (k << 8);
      float vv = cv[p]; int gg = ci[p];
      if (vv > bv || (vv == bv && gg < bg)) { bv = vv; bg = gg; bp = p; }
    }
    waveArgMax3(bv, bg, bp);
    if (lane == 0) { redv[wid] = bv; redg[wid] = bg; redp[wid] = bp; }
    __syncthreads();
    if (tid == 0) {
      float v = redv[0]; int g = redg[0]; int p = redp[0];
      #pragma unroll
      for (int i = 1; i < 4; ++i)
        if (redv[i] > v || (redv[i] == v && redg[i] < g)) { v = redv[i]; g = redg[i]; p = redp[i]; }
      out_val[(blockIdx.x << 5) + it] = v;
      out_idx[(blockIdx.x << 5) + it] = g;
      if (p >= 0) cv[p] = NEG_INF;
    }
    __syncthreads();
  }
}

// ---------------- final: 128 candidates -> top-32, softmax, weighted gather ----------------

__global__ __launch_bounds__(256) void final_kernel(
    const float* __restrict__ c3v, const int* __restrict__ c3i,
    const float* __restrict__ values, float* __restrict__ out)
{
  __shared__ float cv[128];
  __shared__ int   ci[128];
  __shared__ float selv[NRET];
  __shared__ int   seli[NRET];
  __shared__ float attn[NRET];
  int tid = threadIdx.x, wid = tid >> 6, lane = tid & 63;
  if (tid < 128) { cv[tid] = c3v[tid]; ci[tid] = c3i[tid]; }
  __syncthreads();

  if (wid == 0) {
    // wave 0: register tournament over 128 candidates
    float v0 = cv[lane], v1 = cv[lane + 64];
    int   g0 = ci[lane], g1 = ci[lane + 64];
    for (int it = 0; it < NRET; ++it) {
      bool pick1 = (v1 > v0) || (v1 == v0 && g1 < g0);
      float v = pick1 ? v1 : v0;
      int  gi = pick1 ? g1 : g0;
      int code = (lane << 1) | (pick1 ? 1 : 0);
      waveArgMax3(v, gi, code);
      if (lane == (code >> 1)) {
        if (code & 1) v1 = NEG_INF; else v0 = NEG_INF;
      }
      if (lane == 0) { selv[it] = v; seli[it] = gi; }
    }
  }
  __syncthreads();

  if (wid == 0) {
    // softmax over 32 (selv[0] is the max); all 64 lanes active, lanes 32..63 mirror
    int idx = lane & 31;
    float e = expf(selv[idx] - selv[0]);
    float s = e;
    #pragma unroll
    for (int off = 16; off; off >>= 1) s += __shfl_xor(s, off);
    if (lane < 32) attn[lane] = e / s;
  }
  __syncthreads();

  if (tid < VALUE_DIM) {
    float acc = 0.f;
    #pragma unroll
    for (int k = 0; k < NRET; ++k)
      acc += attn[k] * values[(size_t)seli[k] * VALUE_DIM + tid];
    out[tid] = acc;
  }
}

// ---------------- launch ----------------

extern "C" void kernel_launch(void* const* d_in, const int* in_sizes, int n_in,
                              void* d_out, int out_size, void* d_ws, size_t ws_size,
                              hipStream_t stream) {
  const float* query  = (const float*)d_in[0];
  const float* W1     = (const float*)d_in[1];
  const float* b1     = (const float*)d_in[2];
  const float* W2     = (const float*)d_in[3];
  const float* b2     = (const float*)d_in[4];
  const float* ln_g   = (const float*)d_in[5];
  const float* ln_b   = (const float*)d_in[6];
  const float* keys   = (const float*)d_in[7];
  const float* values = (const float*)d_in[8];
  float* out = (float*)d_out;

  // workspace layout (floats)
  float* wsf = (float*)d_ws;
  float* h        = wsf;                    // 512
  float* g        = wsf + 512;              // 512
  float* qn       = wsf + 1024;             // 512
  float* cand_val = wsf + 2048;             // 131072
  int*   cand_idx = (int*)(wsf + 2048 + 131072);       // 131072
  float* c2v      = wsf + 2048 + 262144;    // 4096
  int*   c2i      = (int*)(wsf + 2048 + 262144 + 4096);// 4096
  float* c3v      = wsf + 2048 + 262144 + 8192;        // 128
  int*   c3i      = (int*)(wsf + 2048 + 262144 + 8192 + 128); // 128

  hipLaunchKernelGGL(matvec1_kernel, dim3(128), dim3(256), 0, stream, query, W1, b1, h);
  hipLaunchKernelGGL(matvec2_kernel, dim3(128), dim3(256), 0, stream, h, W2, b2, g);
  hipLaunchKernelGGL(norm_kernel,    dim3(1),   dim3(512), 0, stream, g, ln_g, ln_b, qn);
  hipLaunchKernelGGL(scan_topk,      dim3(SCAN_BLOCKS), dim3(256), 0, stream,
                     keys, qn, cand_val, cand_idx, CAPACITY);
  hipLaunchKernelGGL(merge_topk,     dim3(128), dim3(256), 0, stream,
                     cand_val, cand_idx, c2v, c2i);
  hipLaunchKernelGGL(merge_topk,     dim3(4),   dim3(256), 0, stream,
                     c2v, c2i, c3v, c3i);
  hipLaunchKernelGGL(final_kernel,   dim3(1),   dim3(256), 0, stream,
                     c3v, c3i, values, out);
}

// Round 3
// 299.314 us; speedup vs baseline: 1.5028x; 1.0324x over previous
//
#include <hip/hip_runtime.h>
#include <math.h>

#define KEY_DIM   512
#define VALUE_DIM 128
#define CAPACITY  500000
#define NRET      32
#define LN_EPS    1e-5f
#define NORM_EPS  1e-12f
#define NEG_INF   (-3.402823466e38f)
#define IDX_INF   0x7fffffff

#define SCAN_BLOCKS 2048
#define CHUNK       245    // ceil(500000/2048); rows per wave <= 62 -> 1 reg of sims
#define JMAX        62

// ---------------- cross-lane primitives ----------------

template<int CTRL>
__device__ inline float dppMovF(float x) {
  return __int_as_float(__builtin_amdgcn_update_dpp(0, __float_as_int(x), CTRL, 0xF, 0xF, true));
}

// full 64-lane sum, result in every lane; 4 DPP steps + swizzle(xor16) + shfl(xor32)
__device__ inline float waveSumF(float x) {
  x += dppMovF<0xB1>(x);    // quad_perm [1,0,3,2]  : xor1
  x += dppMovF<0x4E>(x);    // quad_perm [2,3,0,1]  : xor2
  x += dppMovF<0x124>(x);   // row_ror:4            : +quad(+1)
  x += dppMovF<0x128>(x);   // row_ror:8            : +quads(+2,+3) -> 16-sum
  x += __int_as_float(__builtin_amdgcn_ds_swizzle(__float_as_int(x), 0x401F)); // xor16
  x += __shfl_xor(x, 32);                                                      // xor32
  return x;
}

template<int D>
__device__ inline int fetchI(int x) {
  if constexpr (D == 1)       return __builtin_amdgcn_update_dpp(0, x, 0xB1, 0xF, 0xF, true);
  else if constexpr (D == 2)  return __builtin_amdgcn_update_dpp(0, x, 0x4E, 0xF, 0xF, true);
  else if constexpr (D == 4)  return __builtin_amdgcn_ds_swizzle(x, 0x101F);  // xor4
  else if constexpr (D == 8)  return __builtin_amdgcn_ds_swizzle(x, 0x201F);  // xor8
  else if constexpr (D == 16) return __builtin_amdgcn_ds_swizzle(x, 0x401F);  // xor16
  else                        return __shfl_xor(x, 32);                       // xor32
}
template<int D>
__device__ inline float fetchF(float x) { return __int_as_float(fetchI<D>(__float_as_int(x))); }

// butterfly argmax over 64 lanes by (v desc, gi asc); carries payload code
__device__ inline void waveArgMax3(float& v, int& gi, int& code) {
  #pragma unroll
  for (int off = 32; off; off >>= 1) {
    float ov = __shfl_xor(v, off);
    int   og = __shfl_xor(gi, off);
    int   oc = __shfl_xor(code, off);
    if (ov > v || (ov == v && og < gi)) { v = ov; gi = og; code = oc; }
  }
}

__device__ inline float blockSum512(float v, float* red) {
  #pragma unroll
  for (int off = 32; off; off >>= 1) v += __shfl_xor(v, off);
  int wid = threadIdx.x >> 6, lane = threadIdx.x & 63;
  if (lane == 0) red[wid] = v;
  __syncthreads();
  float s = red[0] + red[1] + red[2] + red[3] + red[4] + red[5] + red[6] + red[7];
  __syncthreads();
  return s;
}

// ---------------- MLP kernels ----------------

__global__ __launch_bounds__(256) void matvec1_kernel(
    const float* __restrict__ query, const float* __restrict__ W1,
    const float* __restrict__ b1, float* __restrict__ h)
{
  int tid = threadIdx.x, wid = tid >> 6, lane = tid & 63;
  int row = (blockIdx.x << 2) + wid;
  const float4* q4 = (const float4*)query;
  const float4* wrow = (const float4*)(W1 + (size_t)row * KEY_DIM);
  float4 a0 = wrow[lane],      q0 = q4[lane];
  float4 a1 = wrow[lane + 64], q1 = q4[lane + 64];
  float acc = a0.x*q0.x + a0.y*q0.y + a0.z*q0.z + a0.w*q0.w
            + a1.x*q1.x + a1.y*q1.y + a1.z*q1.z + a1.w*q1.w;
  #pragma unroll
  for (int off = 32; off; off >>= 1) acc += __shfl_xor(acc, off);
  if (lane == 0) {
    float x = acc + b1[row];
    h[row] = x / (1.f + expf(-x));   // silu
  }
}

__global__ __launch_bounds__(256) void matvec2_kernel(
    const float* __restrict__ h, const float* __restrict__ W2,
    const float* __restrict__ b2, float* __restrict__ g)
{
  int tid = threadIdx.x, wid = tid >> 6, lane = tid & 63;
  int row = (blockIdx.x << 2) + wid;
  const float4* h4 = (const float4*)h;
  const float4* wrow = (const float4*)(W2 + (size_t)row * KEY_DIM);
  float4 a0 = wrow[lane],      q0 = h4[lane];
  float4 a1 = wrow[lane + 64], q1 = h4[lane + 64];
  float acc = a0.x*q0.x + a0.y*q0.y + a0.z*q0.z + a0.w*q0.w
            + a1.x*q1.x + a1.y*q1.y + a1.z*q1.z + a1.w*q1.w;
  #pragma unroll
  for (int off = 32; off; off >>= 1) acc += __shfl_xor(acc, off);
  if (lane == 0) g[row] = acc + b2[row];
}

__global__ __launch_bounds__(512) void norm_kernel(
    const float* __restrict__ g, const float* __restrict__ ln_g,
    const float* __restrict__ ln_b, float* __restrict__ qn)
{
  __shared__ float red[8];
  int tid = threadIdx.x;
  float x  = g[tid];
  float mu = blockSum512(x, red) * (1.f / 512.f);
  float d  = x - mu;
  float var = blockSum512(d * d, red) * (1.f / 512.f);
  float y  = d * (1.f / sqrtf(var + LN_EPS)) * ln_g[tid] + ln_b[tid];
  float nsq = blockSum512(y * y, red);
  float n  = fmaxf(sqrtf(nsq), NORM_EPS);
  qn[tid] = y / n;
}

// ---------------- scan: cosine sims + per-wave bitonic top-32 ----------------
// 2048 blocks x 256; wave wid owns rows s0 + wid + 4j, j=0..61; sim of row j -> lane j

__global__ __launch_bounds__(256) void scan_topk(
    const float* __restrict__ keys, const float* __restrict__ qn,
    float* __restrict__ cand_val, int* __restrict__ cand_idx, int C)
{
  int tid = threadIdx.x, wid = tid >> 6, lane = tid & 63;
  int s0  = blockIdx.x * CHUNK;

  const float4* q4 = (const float4*)qn;
  float4 q0 = q4[lane];
  float4 q1 = q4[lane + 64];
  const float4* keys4 = (const float4*)keys;

  float v  = NEG_INF;
  int   gi = IDX_INF;

  #pragma unroll 2
  for (int j = 0; j < JMAX; ++j) {
    int row   = s0 + wid + (j << 2);
    bool valid = row < C;
    int rc    = valid ? row : (C - 1);
    const float4* kr = keys4 + (size_t)rc * 128;
    float4 a = kr[lane];
    float4 c = kr[lane + 64];
    float dot = a.x*q0.x + a.y*q0.y + a.z*q0.z + a.w*q0.w
              + c.x*q1.x + c.y*q1.y + c.z*q1.z + c.w*q1.w;
    float ss  = a.x*a.x + a.y*a.y + a.z*a.z + a.w*a.w
              + c.x*c.x + c.y*c.y + c.z*c.z + c.w*c.w;
    dot = waveSumF(dot);
    ss  = waveSumF(ss);
    float sim = dot / fmaxf(sqrtf(ss), NORM_EPS);   // same value in all 64 lanes
    if (lane == j) {
      v  = valid ? sim : NEG_INF;
      gi = valid ? row : IDX_INF;
    }
  }

  // bitonic sort of 64 (v, gi) pairs, descending by (v desc, gi asc)
  #define BSTAGE(D, K) { \
    float ov = fetchF<D>(v); int og = fetchI<D>(gi); \
    bool keepL = ((lane & (D)) == 0) == ((lane & (K)) == 0); \
    bool ogt = (ov > v) || (ov == v && og < gi); \
    bool take = keepL ? ogt : !ogt; \
    if (take) { v = ov; gi = og; } }

  BSTAGE(1,2)
  BSTAGE(2,4)  BSTAGE(1,4)
  BSTAGE(4,8)  BSTAGE(2,8)  BSTAGE(1,8)
  BSTAGE(8,16) BSTAGE(4,16) BSTAGE(2,16) BSTAGE(1,16)
  BSTAGE(16,32) BSTAGE(8,32) BSTAGE(4,32) BSTAGE(2,32) BSTAGE(1,32)
  BSTAGE(32,64) BSTAGE(16,64) BSTAGE(8,64) BSTAGE(4,64) BSTAGE(2,64) BSTAGE(1,64)
  #undef BSTAGE

  if (lane < NRET) {
    int w = (blockIdx.x << 2) + wid;
    cand_val[w * NRET + lane] = v;
    cand_idx[w * NRET + lane] = gi;
  }
}

// ---------------- merge: per block, 1024 candidates -> top-32 ----------------

__global__ __launch_bounds__(256) void merge_topk(
    const float* __restrict__ in_val, const int* __restrict__ in_idx,
    float* __restrict__ out_val, int* __restrict__ out_idx)
{
  __shared__ float cv[1024];
  __shared__ int   ci[1024];
  __shared__ float redv[4];
  __shared__ int   redg[4];
  __shared__ int   redp[4];
  int tid = threadIdx.x, wid = tid >> 6, lane = tid & 63;
  int base = blockIdx.x << 10;
  for (int t = tid; t < 1024; t += 256) { cv[t] = in_val[base + t]; ci[t] = in_idx[base + t]; }
  __syncthreads();

  for (int it = 0; it < NRET; ++it) {
    float bv = NEG_INF; int bg = IDX_INF; int bp = -1;
    #pragma unroll
    for (int k = 0; k < 4; ++k) {
      int p = tid + (k << 8);
      float vv = cv[p]; int gg = ci[p];
      if (vv > bv || (vv == bv && gg < bg)) { bv = vv; bg = gg; bp = p; }
    }
    waveArgMax3(bv, bg, bp);
    if (lane == 0) { redv[wid] = bv; redg[wid] = bg; redp[wid] = bp; }
    __syncthreads();
    if (tid == 0) {
      float vv = redv[0]; int gg = redg[0]; int pp = redp[0];
      #pragma unroll
      for (int i = 1; i < 4; ++i)
        if (redv[i] > vv || (redv[i] == vv && redg[i] < gg)) { vv = redv[i]; gg = redg[i]; pp = redp[i]; }
      out_val[(blockIdx.x << 5) + it] = vv;
      out_idx[(blockIdx.x << 5) + it] = gg;
      if (pp >= 0) cv[pp] = NEG_INF;
    }
    __syncthreads();
  }
}

// ---------------- final: 256 candidates -> top-32, softmax, weighted gather ----------------

__global__ __launch_bounds__(256) void final_kernel(
    const float* __restrict__ c3v, const int* __restrict__ c3i,
    const float* __restrict__ values, float* __restrict__ out)
{
  __shared__ float selv[NRET];
  __shared__ int   seli[NRET];
  __shared__ float attn[NRET];
  int tid = threadIdx.x, wid = tid >> 6, lane = tid & 63;

  if (wid == 0) {
    float v0 = c3v[lane], v1 = c3v[lane + 64], v2 = c3v[lane + 128], v3 = c3v[lane + 192];
    int   g0 = c3i[lane], g1 = c3i[lane + 64], g2 = c3i[lane + 128], g3 = c3i[lane + 192];
    for (int it = 0; it < NRET; ++it) {
      float bv = v0; int bg = g0; int bc = 0;
      if (v1 > bv || (v1 == bv && g1 < bg)) { bv = v1; bg = g1; bc = 1; }
      if (v2 > bv || (v2 == bv && g2 < bg)) { bv = v2; bg = g2; bc = 2; }
      if (v3 > bv || (v3 == bv && g3 < bg)) { bv = v3; bg = g3; bc = 3; }
      int code = (lane << 2) | bc;
      waveArgMax3(bv, bg, code);
      if (lane == (code >> 2)) {
        int s = code & 3;
        if (s == 0) v0 = NEG_INF; else if (s == 1) v1 = NEG_INF;
        else if (s == 2) v2 = NEG_INF; else v3 = NEG_INF;
      }
      if (lane == 0) { selv[it] = bv; seli[it] = bg; }
    }
  }
  __syncthreads();

  if (tid < NRET) {
    float e = expf(selv[tid] - selv[0]);     // selv[0] is the max
    float s = e;
    #pragma unroll
    for (int off = 16; off; off >>= 1) s += __shfl_xor(s, off);
    attn[tid] = e / s;
  }
  __syncthreads();

  if (tid < VALUE_DIM) {
    float acc = 0.f;
    #pragma unroll
    for (int k = 0; k < NRET; ++k)
      acc += attn[k] * values[(size_t)seli[k] * VALUE_DIM + tid];
    out[tid] = acc;
  }
}

// ---------------- launch ----------------

extern "C" void kernel_launch(void* const* d_in, const int* in_sizes, int n_in,
                              void* d_out, int out_size, void* d_ws, size_t ws_size,
                              hipStream_t stream) {
  const float* query  = (const float*)d_in[0];
  const float* W1     = (const float*)d_in[1];
  const float* b1     = (const float*)d_in[2];
  const float* W2     = (const float*)d_in[3];
  const float* b2     = (const float*)d_in[4];
  const float* ln_g   = (const float*)d_in[5];
  const float* ln_b   = (const float*)d_in[6];
  const float* keys   = (const float*)d_in[7];
  const float* values = (const float*)d_in[8];
  float* out = (float*)d_out;

  // workspace (floats): qn | h | g | cand_val | cand_idx | c2v | c2i | c3v | c3i
  float* wsf = (float*)d_ws;
  float* qn       = wsf;                                   // 512
  float* h        = wsf + 512;                             // 512
  float* g        = wsf + 1024;                            // 512
  float* cand_val = wsf + 2048;                            // 262144
  int*   cand_idx = (int*)(wsf + 2048 + 262144);           // 262144
  float* c2v      = wsf + 2048 + 524288;                   // 8192
  int*   c2i      = (int*)(wsf + 2048 + 524288 + 8192);    // 8192
  float* c3v      = wsf + 2048 + 524288 + 16384;           // 256
  int*   c3i      = (int*)(wsf + 2048 + 524288 + 16384 + 256); // 256

  hipLaunchKernelGGL(matvec1_kernel, dim3(128), dim3(256), 0, stream, query, W1, b1, h);
  hipLaunchKernelGGL(matvec2_kernel, dim3(128), dim3(256), 0, stream, h, W2, b2, g);
  hipLaunchKernelGGL(norm_kernel,    dim3(1),   dim3(512), 0, stream, g, ln_g, ln_b, qn);
  hipLaunchKernelGGL(scan_topk,      dim3(SCAN_BLOCKS), dim3(256), 0, stream,
                     keys, qn, cand_val, cand_idx, CAPACITY);
  hipLaunchKernelGGL(merge_topk,     dim3(256), dim3(256), 0, stream,
                     cand_val, cand_idx, c2v, c2i);
  hipLaunchKernelGGL(merge_topk,     dim3(8),   dim3(256), 0, stream,
                     c2v, c2i, c3v, c3i);
  hipLaunchKernelGGL(final_kernel,   dim3(1),   dim3(256), 0, stream,
                     c3v, c3i, values, out);
}

// Round 4
// 278.936 us; speedup vs baseline: 1.6126x; 1.0731x over previous
//
#include <hip/hip_runtime.h>
#include <math.h>

#define KEY_DIM   512
#define VALUE_DIM 128
#define CAP       500000
#define NRET      32
#define LN_EPS    1e-5f
#define NORM_EPS  1e-12f
#define NEG_INF   (-3.402823466e38f)
#define IDX_INF   0x7fffffff

#define SCAN_BLOCKS 489              // ceil(500000 / 1024); wave = 256 rows, block = 1024 rows
#define NCAND       (SCAN_BLOCKS * 4 * 32)   // 62592
#define M1_BLOCKS   62               // ceil(NCAND / 1024)
#define N2          (M1_BLOCKS * 32) // 1984

// ---------------- cross-lane primitives ----------------

template<int CTRL>
__device__ inline float dppMovF(float x) {
  return __int_as_float(__builtin_amdgcn_update_dpp(0, __float_as_int(x), CTRL, 0xF, 0xF, true));
}

// full 64-lane sum, result in every lane
__device__ inline float waveSumF(float x) {
  x += dppMovF<0xB1>(x);    // quad_perm xor1
  x += dppMovF<0x4E>(x);    // quad_perm xor2
  x += dppMovF<0x124>(x);   // row_ror:4
  x += dppMovF<0x128>(x);   // row_ror:8  -> row-of-16 sum
  x += __int_as_float(__builtin_amdgcn_ds_swizzle(__float_as_int(x), 0x401F)); // xor16
  x += __shfl_xor(x, 32);                                                      // xor32
  return x;
}

template<int D>
__device__ inline int fetchI(int x) {
  if constexpr (D == 1)       return __builtin_amdgcn_update_dpp(0, x, 0xB1, 0xF, 0xF, true);
  else if constexpr (D == 2)  return __builtin_amdgcn_update_dpp(0, x, 0x4E, 0xF, 0xF, true);
  else if constexpr (D == 4)  return __builtin_amdgcn_ds_swizzle(x, 0x101F);  // xor4
  else if constexpr (D == 8)  return __builtin_amdgcn_ds_swizzle(x, 0x201F);  // xor8
  else if constexpr (D == 16) return __builtin_amdgcn_ds_swizzle(x, 0x401F);  // xor16
  else                        return __shfl_xor(x, 32);                       // xor32
}
template<int D>
__device__ inline float fetchF(float x) { return __int_as_float(fetchI<D>(__float_as_int(x))); }

// one butterfly step of argmax by (v desc, gi asc) carrying payload code
template<int D>
__device__ inline void amStep(float& v, int& g, int& c) {
  float ov = fetchF<D>(v); int og = fetchI<D>(g); int oc = fetchI<D>(c);
  if (ov > v || (ov == v && og < g)) { v = ov; g = og; c = oc; }
}
__device__ inline void waveArgMax3(float& v, int& g, int& c) {
  amStep<1>(v, g, c); amStep<2>(v, g, c); amStep<4>(v, g, c);
  amStep<8>(v, g, c); amStep<16>(v, g, c); amStep<32>(v, g, c);
}

// bitonic compare-exchange, partner at lane^D (same register)
template<int D>
__device__ inline void ceStageLane(float& v, int& gi, bool desc, int lane) {
  float ov = fetchF<D>(v); int og = fetchI<D>(gi);
  bool better  = (ov > v) || (ov == v && og < gi);
  bool amLower = (lane & D) == 0;
  bool keepMax = (amLower == desc);
  if (keepMax == better) { v = ov; gi = og; }
}

// bitonic compare-exchange between two registers (A holds the lower element id)
__device__ inline void ceStageReg(float& vA, int& gA, float& vB, int& gB, bool desc) {
  bool better = (vB > vA) || (vB == vA && gB < gA);
  bool sw = (better == desc);
  float tv = sw ? vB : vA; vB = sw ? vA : vB; vA = tv;
  int   tg = sw ? gB : gA; gB = sw ? gA : gB; gA = tg;
}

// ---------------- MLP matvecs ----------------

__global__ __launch_bounds__(256) void matvec1_kernel(
    const float* __restrict__ query, const float* __restrict__ W1,
    const float* __restrict__ b1, float* __restrict__ h)
{
  int tid = threadIdx.x, wid = tid >> 6, lane = tid & 63;
  int row = (blockIdx.x << 2) + wid;
  const float4* q4 = (const float4*)query;
  const float4* wrow = (const float4*)(W1 + (size_t)row * KEY_DIM);
  float4 a0 = wrow[lane],      q0 = q4[lane];
  float4 a1 = wrow[lane + 64], q1 = q4[lane + 64];
  float acc = a0.x*q0.x + a0.y*q0.y + a0.z*q0.z + a0.w*q0.w
            + a1.x*q1.x + a1.y*q1.y + a1.z*q1.z + a1.w*q1.w;
  acc = waveSumF(acc);
  if (lane == 0) {
    float x = acc + b1[row];
    h[row] = x / (1.f + expf(-x));   // silu
  }
}

__global__ __launch_bounds__(256) void matvec2_kernel(
    const float* __restrict__ h, const float* __restrict__ W2,
    const float* __restrict__ b2, float* __restrict__ g)
{
  int tid = threadIdx.x, wid = tid >> 6, lane = tid & 63;
  int row = (blockIdx.x << 2) + wid;
  const float4* h4 = (const float4*)h;
  const float4* wrow = (const float4*)(W2 + (size_t)row * KEY_DIM);
  float4 a0 = wrow[lane],      q0 = h4[lane];
  float4 a1 = wrow[lane + 64], q1 = h4[lane + 64];
  float acc = a0.x*q0.x + a0.y*q0.y + a0.z*q0.z + a0.w*q0.w
            + a1.x*q1.x + a1.y*q1.y + a1.z*q1.z + a1.w*q1.w;
  acc = waveSumF(acc);
  if (lane == 0) g[row] = acc + b2[row];
}

// ---------------- scan: inline LN/L2 + cosine sims + per-wave sort-256 top-32 ----------------
// 489 blocks x 256; wave owns 256 consecutive rows; batches of 8 rows (16 loads in flight)

__global__ __launch_bounds__(256, 4) void scan_kernel(
    const float* __restrict__ keys, const float* __restrict__ g,
    const float* __restrict__ ln_g, const float* __restrict__ ln_b,
    float* __restrict__ cand_val, int* __restrict__ cand_idx)
{
  const int tid = threadIdx.x, wid = tid >> 6, lane = tid & 63;

  // ---- per-wave LayerNorm + L2-normalize of g[512] -> q0,q1 (lane layout matches keys reads) ----
  const float4* g4 = (const float4*)g;
  float4 x0 = g4[lane], x1 = g4[lane + 64];
  float psum = x0.x + x0.y + x0.z + x0.w + x1.x + x1.y + x1.z + x1.w;
  float mu = waveSumF(psum) * (1.f / 512.f);
  float4 d0, d1;
  d0.x = x0.x - mu; d0.y = x0.y - mu; d0.z = x0.z - mu; d0.w = x0.w - mu;
  d1.x = x1.x - mu; d1.y = x1.y - mu; d1.z = x1.z - mu; d1.w = x1.w - mu;
  float pvar = d0.x*d0.x + d0.y*d0.y + d0.z*d0.z + d0.w*d0.w
             + d1.x*d1.x + d1.y*d1.y + d1.z*d1.z + d1.w*d1.w;
  float var  = waveSumF(pvar) * (1.f / 512.f);
  float rstd = 1.f / sqrtf(var + LN_EPS);
  const float4* lg4 = (const float4*)ln_g;
  const float4* lb4 = (const float4*)ln_b;
  float4 a0 = lg4[lane], a1 = lg4[lane + 64];
  float4 b0 = lb4[lane], b1 = lb4[lane + 64];
  float4 y0, y1;
  y0.x = d0.x*rstd*a0.x + b0.x; y0.y = d0.y*rstd*a0.y + b0.y;
  y0.z = d0.z*rstd*a0.z + b0.z; y0.w = d0.w*rstd*a0.w + b0.w;
  y1.x = d1.x*rstd*a1.x + b1.x; y1.y = d1.y*rstd*a1.y + b1.y;
  y1.z = d1.z*rstd*a1.z + b1.z; y1.w = d1.w*rstd*a1.w + b1.w;
  float pn  = y0.x*y0.x + y0.y*y0.y + y0.z*y0.z + y0.w*y0.w
            + y1.x*y1.x + y1.y*y1.y + y1.z*y1.z + y1.w*y1.w;
  float nsq = waveSumF(pn);
  float nf  = 1.f / fmaxf(sqrtf(nsq), NORM_EPS);
  float4 q0, q1;
  q0.x = y0.x*nf; q0.y = y0.y*nf; q0.z = y0.z*nf; q0.w = y0.w*nf;
  q1.x = y1.x*nf; q1.y = y1.y*nf; q1.z = y1.z*nf; q1.w = y1.w*nf;

  // ---- scan 256 rows: 4 segments x 8 batches x 8 rows ----
  const char* kl = (const char*)keys + (size_t)lane * 16;   // lane's 16B column slice
  const int wrow0 = (blockIdx.x << 10) + (wid << 8);

  float sv[4]; int sg[4];

  #pragma unroll
  for (int seg = 0; seg < 4; ++seg) {
    const int segbase = wrow0 + (seg << 6);
    float simreg = NEG_INF;
    #pragma unroll 1
    for (int bi = 0; bi < 8; ++bi) {
      const int r0 = segbase + (bi << 3);
      float4 A[8], B[8];
      #pragma unroll
      for (int i = 0; i < 8; ++i) {
        int rr = min(r0 + i, CAP - 1);
        const char* rp = kl + (size_t)rr * 2048;
        A[i] = *(const float4*)rp;
        B[i] = *(const float4*)(rp + 1024);
      }
      float dt[8], sq[8];
      #pragma unroll
      for (int i = 0; i < 8; ++i) {
        dt[i] = A[i].x*q0.x + A[i].y*q0.y + A[i].z*q0.z + A[i].w*q0.w
              + B[i].x*q1.x + B[i].y*q1.y + B[i].z*q1.z + B[i].w*q1.w;
        sq[i] = A[i].x*A[i].x + A[i].y*A[i].y + A[i].z*A[i].z + A[i].w*A[i].w
              + B[i].x*B[i].x + B[i].y*B[i].y + B[i].z*B[i].z + B[i].w*B[i].w;
      }
      #pragma unroll
      for (int i = 0; i < 8; ++i) { dt[i] = waveSumF(dt[i]); sq[i] = waveSumF(sq[i]); }
      #pragma unroll
      for (int i = 0; i < 8; ++i) {
        float sim = dt[i] / fmaxf(sqrtf(sq[i]), NORM_EPS);
        bool ok = (r0 + i) < CAP;
        sim = ok ? sim : NEG_INF;
        int rb = (bi << 3) + i;               // 0..63 within segment
        simreg = (lane == rb) ? sim : simreg;
      }
    }
    sv[seg] = simreg;
    sg[seg] = segbase + lane;                 // row index (may be >= CAP only when v == NEG_INF)
  }

  // ---- bitonic sort of 256 (element id e = seg*64 + lane), descending by (v, gi asc) ----
  #define LST4(D, A0, A1, A2, A3) \
    ceStageLane<D>(sv[0], sg[0], A0, lane); \
    ceStageLane<D>(sv[1], sg[1], A1, lane); \
    ceStageLane<D>(sv[2], sg[2], A2, lane); \
    ceStageLane<D>(sv[3], sg[3], A3, lane);

  { bool dm = (lane & 2) == 0;  LST4(1, dm,dm,dm,dm) }                               // m=2
  { bool dm = (lane & 4) == 0;  LST4(2, dm,dm,dm,dm)  LST4(1, dm,dm,dm,dm) }         // m=4
  { bool dm = (lane & 8) == 0;  LST4(4, dm,dm,dm,dm)  LST4(2, dm,dm,dm,dm)
                                LST4(1, dm,dm,dm,dm) }                               // m=8
  { bool dm = (lane & 16) == 0; LST4(8, dm,dm,dm,dm)  LST4(4, dm,dm,dm,dm)
                                LST4(2, dm,dm,dm,dm)  LST4(1, dm,dm,dm,dm) }         // m=16
  { bool dm = (lane & 32) == 0; LST4(16, dm,dm,dm,dm) LST4(8, dm,dm,dm,dm)
                                LST4(4, dm,dm,dm,dm)  LST4(2, dm,dm,dm,dm)
                                LST4(1, dm,dm,dm,dm) }                               // m=32
  // m=64: desc per reg = ((e&64)==0) -> T,F,T,F
  LST4(32, true,false,true,false) LST4(16, true,false,true,false)
  LST4(8,  true,false,true,false) LST4(4,  true,false,true,false)
  LST4(2,  true,false,true,false) LST4(1,  true,false,true,false)
  // m=128: d=64 cross-reg pairs (0,1) desc=T, (2,3) desc=F; then lanes, desc T,T,F,F
  ceStageReg(sv[0], sg[0], sv[1], sg[1], true);
  ceStageReg(sv[2], sg[2], sv[3], sg[3], false);
  LST4(32, true,true,false,false) LST4(16, true,true,false,false)
  LST4(8,  true,true,false,false) LST4(4,  true,true,false,false)
  LST4(2,  true,true,false,false) LST4(1,  true,true,false,false)
  // m=256: d=128, then d=64, then lanes (all desc)
  ceStageReg(sv[0], sg[0], sv[2], sg[2], true);
  ceStageReg(sv[1], sg[1], sv[3], sg[3], true);
  ceStageReg(sv[0], sg[0], sv[1], sg[1], true);
  ceStageReg(sv[2], sg[2], sv[3], sg[3], true);
  LST4(32, true,true,true,true) LST4(16, true,true,true,true)
  LST4(8,  true,true,true,true) LST4(4,  true,true,true,true)
  LST4(2,  true,true,true,true) LST4(1,  true,true,true,true)
  #undef LST4

  // top-32 of this wave = reg0, lanes 0..31
  if (lane < NRET) {
    int w = (blockIdx.x << 2) + wid;
    cand_val[w * NRET + lane] = sv[0];
    cand_idx[w * NRET + lane] = sg[0];
  }
}

// ---------------- merge: 1024 candidates/block -> block top-32 ----------------

__global__ __launch_bounds__(256) void merge_kernel(
    const float* __restrict__ in_val, const int* __restrict__ in_idx, int n,
    float* __restrict__ out_val, int* __restrict__ out_idx)
{
  __shared__ float lv[128];
  __shared__ int   li[128];
  int tid = threadIdx.x, wid = tid >> 6, lane = tid & 63;

  float vs[4]; int gs[4];
  int base = (blockIdx.x << 10) + (wid << 8);
  #pragma unroll
  for (int k = 0; k < 4; ++k) {
    int idx = base + (k << 6) + lane;
    bool ok = idx < n;
    vs[k] = ok ? in_val[idx] : NEG_INF;
    gs[k] = ok ? in_idx[idx] : IDX_INF;
  }
  // per-wave top-32 (4-slot tournament)
  for (int it = 0; it < NRET; ++it) {
    float bv = vs[0]; int bg = gs[0]; int bs = 0;
    #pragma unroll
    for (int k = 1; k < 4; ++k)
      if (vs[k] > bv || (vs[k] == bv && gs[k] < bg)) { bv = vs[k]; bg = gs[k]; bs = k; }
    int code = (lane << 2) | bs;
    waveArgMax3(bv, bg, code);
    if (lane == (code >> 2)) {
      int s = code & 3;
      if (s == 0) vs[0] = NEG_INF; else if (s == 1) vs[1] = NEG_INF;
      else if (s == 2) vs[2] = NEG_INF; else vs[3] = NEG_INF;
    }
    if (lane == 0) { lv[(wid << 5) + it] = bv; li[(wid << 5) + it] = bg; }
  }
  __syncthreads();
  // wave0: 128 -> 32
  if (wid == 0) {
    float c0 = lv[lane], c1 = lv[64 + lane];
    int   h0 = li[lane], h1 = li[64 + lane];
    for (int it = 0; it < NRET; ++it) {
      bool p1 = (c1 > c0) || (c1 == c0 && h1 < h0);
      float bv = p1 ? c1 : c0; int bg = p1 ? h1 : h0;
      int code = (lane << 1) | (p1 ? 1 : 0);
      waveArgMax3(bv, bg, code);
      if (lane == (code >> 1)) { if (code & 1) c1 = NEG_INF; else c0 = NEG_INF; }
      if (lane == 0) {
        out_val[(blockIdx.x << 5) + it] = bv;
        out_idx[(blockIdx.x << 5) + it] = bg;
      }
    }
  }
}

// ---------------- final: N2 -> top-32, softmax, weighted gather ----------------

__global__ __launch_bounds__(256) void final_kernel(
    const float* __restrict__ c2v, const int* __restrict__ c2i, int n,
    const float* __restrict__ values, float* __restrict__ out)
{
  __shared__ float lv[128];
  __shared__ int   li[128];
  __shared__ float selv[NRET];
  __shared__ int   seli[NRET];
  __shared__ float attn[NRET];
  int tid = threadIdx.x, wid = tid >> 6, lane = tid & 63;

  float vs[8]; int gs[8];
  int base = (wid << 9);
  #pragma unroll
  for (int k = 0; k < 8; ++k) {
    int idx = base + (k << 6) + lane;
    bool ok = idx < n;
    vs[k] = ok ? c2v[idx] : NEG_INF;
    gs[k] = ok ? c2i[idx] : IDX_INF;
  }
  for (int it = 0; it < NRET; ++it) {
    float bv = vs[0]; int bg = gs[0]; int bs = 0;
    #pragma unroll
    for (int k = 1; k < 8; ++k)
      if (vs[k] > bv || (vs[k] == bv && gs[k] < bg)) { bv = vs[k]; bg = gs[k]; bs = k; }
    int code = (lane << 3) | bs;
    waveArgMax3(bv, bg, code);
    if (lane == (code >> 3)) {
      int s = code & 7;
      #pragma unroll
      for (int k = 0; k < 8; ++k) if (k == s) vs[k] = NEG_INF;
    }
    if (lane == 0) { lv[(wid << 5) + it] = bv; li[(wid << 5) + it] = bg; }
  }
  __syncthreads();
  if (wid == 0) {
    float c0 = lv[lane], c1 = lv[64 + lane];
    int   h0 = li[lane], h1 = li[64 + lane];
    for (int it = 0; it < NRET; ++it) {
      bool p1 = (c1 > c0) || (c1 == c0 && h1 < h0);
      float bv = p1 ? c1 : c0; int bg = p1 ? h1 : h0;
      int code = (lane << 1) | (p1 ? 1 : 0);
      waveArgMax3(bv, bg, code);
      if (lane == (code >> 1)) { if (code & 1) c1 = NEG_INF; else c0 = NEG_INF; }
      if (lane == 0) { selv[it] = bv; seli[it] = bg; }
    }
  }
  __syncthreads();
  if (tid < NRET) {
    float e = expf(selv[tid] - selv[0]);   // selv[0] is the max
    float s = e;
    #pragma unroll
    for (int off = 16; off; off >>= 1) s += __shfl_xor(s, off);
    attn[tid] = e / s;
  }
  __syncthreads();
  if (tid < VALUE_DIM) {
    float acc = 0.f;
    #pragma unroll
    for (int k = 0; k < NRET; ++k)
      acc += attn[k] * values[(size_t)seli[k] * VALUE_DIM + tid];
    out[tid] = acc;
  }
}

// ---------------- launch ----------------

extern "C" void kernel_launch(void* const* d_in, const int* in_sizes, int n_in,
                              void* d_out, int out_size, void* d_ws, size_t ws_size,
                              hipStream_t stream) {
  const float* query  = (const float*)d_in[0];
  const float* W1     = (const float*)d_in[1];
  const float* b1     = (const float*)d_in[2];
  const float* W2     = (const float*)d_in[3];
  const float* b2     = (const float*)d_in[4];
  const float* ln_g   = (const float*)d_in[5];
  const float* ln_b   = (const float*)d_in[6];
  const float* keys   = (const float*)d_in[7];
  const float* values = (const float*)d_in[8];
  float* out = (float*)d_out;

  float* wsf = (float*)d_ws;
  float* h        = wsf;                               // 512
  float* g        = wsf + 512;                         // 512
  float* cand_val = wsf + 1024;                        // NCAND
  int*   cand_idx = (int*)(wsf + 1024 + NCAND);        // NCAND
  float* c2v      = wsf + 1024 + 2 * NCAND;            // N2
  int*   c2i      = (int*)(wsf + 1024 + 2 * NCAND + N2); // N2

  hipLaunchKernelGGL(matvec1_kernel, dim3(128), dim3(256), 0, stream, query, W1, b1, h);
  hipLaunchKernelGGL(matvec2_kernel, dim3(128), dim3(256), 0, stream, h, W2, b2, g);
  hipLaunchKernelGGL(scan_kernel, dim3(SCAN_BLOCKS), dim3(256), 0, stream,
                     keys, g, ln_g, ln_b, cand_val, cand_idx);
  hipLaunchKernelGGL(merge_kernel, dim3(M1_BLOCKS), dim3(256), 0, stream,
                     cand_val, cand_idx, NCAND, c2v, c2i);
  hipLaunchKernelGGL(final_kernel, dim3(1), dim3(256), 0, stream,
                     c2v, c2i, N2, values, out);
}